// Round 3
// baseline (279.064 us; speedup 1.0000x reference)
//
#include <hip/hip_runtime.h>

// MultiLabelSoftMax: B=4096 rows, C=8192 classes, K=8 positives/row.
// out = (1/(B*K)) * sum_{b,k} [ log(exp(p_bk) + sum_neg_b) - p_bk ]
// where sum_neg_b = sum_c exp(pred[b,c]) - sum_k exp(p_bk).
//
// Single fused kernel: 2048 blocks x 2 rows (one co-resident pass,
// 32 waves/CU). Per-block loss -> partial[]; last block (ticket via
// atomic counter) reduces 2048 partials and writes the scalar.
// Cross-XCD visibility: __threadfence release (producer) / acquire
// (consumer) around the ticket — rocPRIM decoupled-lookback pattern.

constexpr int B = 4096;
constexpr int C = 8192;
constexpr int K = 8;
constexpr int BLOCK = 256;                 // 4 waves of 64
constexpr int RPB = 2;                     // rows per block
constexpr int GRID = B / RPB;              // 2048
constexpr int VPT = C / 4 / BLOCK;         // 8 float4 per thread per row

__global__ __launch_bounds__(BLOCK)
void mlsm_fused(const float* __restrict__ pred,
                const int* __restrict__ labels,
                float* __restrict__ partial,
                unsigned int* __restrict__ counter,
                float* __restrict__ out) {
    const int tid = threadIdx.x;
    __shared__ float wave_sum[RPB][4];
    __shared__ bool is_last;

    // ---- stream both rows: sum of exp per row ----
    for (int r = 0; r < RPB; ++r) {
        const int b = blockIdx.x * RPB + r;
        const float4* row4 =
            reinterpret_cast<const float4*>(pred + (size_t)b * C);

        float4 v[VPT];
#pragma unroll
        for (int i = 0; i < VPT; ++i)
            v[i] = row4[tid + i * BLOCK];

        float s0 = 0.f, s1 = 0.f, s2 = 0.f, s3 = 0.f;
#pragma unroll
        for (int i = 0; i < VPT; ++i) {
            s0 += __expf(v[i].x);
            s1 += __expf(v[i].y);
            s2 += __expf(v[i].z);
            s3 += __expf(v[i].w);
        }
        float s = (s0 + s1) + (s2 + s3);
#pragma unroll
        for (int off = 32; off > 0; off >>= 1)
            s += __shfl_down(s, off, 64);
        if ((tid & 63) == 0) wave_sum[r][tid >> 6] = s;
    }
    __syncthreads();

    // ---- epilogue: lanes 0..15 = (row g = tid>>3, positive k = tid&7) ----
    if (tid < RPB * K) {
        const int g = tid >> 3;
        const int k = tid & 7;
        const int b = blockIdx.x * RPB + g;
        const float total = (wave_sum[g][0] + wave_sum[g][1]) +
                            (wave_sum[g][2] + wave_sum[g][3]);

        const int cls = labels[b * K + k];
        const float p = pred[(size_t)b * C + cls];  // L2-hot (just streamed)
        const float e = __expf(p);

        float sum_pos = e;
#pragma unroll
        for (int m = 1; m < K; m <<= 1)
            sum_pos += __shfl_xor(sum_pos, m, K);   // within 8-lane group

        const float sum_neg = total - sum_pos;
        float term = __logf(e + sum_neg) - p;
#pragma unroll
        for (int m = 1; m < K; m <<= 1)
            term += __shfl_xor(term, m, K);         // per-row sum on all 8 lanes

        const float other = __shfl(term, 8, 64);    // row-1 sum from lane 8
        if (tid == 0) {
            partial[blockIdx.x] = term + other;
            __threadfence();                        // release: partial visible
            unsigned int old = atomicAdd(counter, 1u);
            is_last = (old == (unsigned int)(GRID - 1));
        }
    }
    __syncthreads();

    // ---- last block reduces all 2048 partials ----
    if (is_last) {
        __threadfence();                            // acquire: invalidate caches
        const float4* p4 = reinterpret_cast<const float4*>(partial);
        float s = 0.f;
#pragma unroll
        for (int i = 0; i < GRID / 4 / BLOCK; ++i) {  // 2 float4 per thread
            float4 v = p4[tid + i * BLOCK];
            s += (v.x + v.y) + (v.z + v.w);
        }
#pragma unroll
        for (int off = 32; off > 0; off >>= 1)
            s += __shfl_down(s, off, 64);
        if ((tid & 63) == 0) wave_sum[0][tid >> 6] = s;
        __syncthreads();
        if (tid == 0)
            out[0] = ((wave_sum[0][0] + wave_sum[0][1]) +
                      (wave_sum[0][2] + wave_sum[0][3])) *
                     (1.0f / (float)(B * K));
    }
}

extern "C" void kernel_launch(void* const* d_in, const int* in_sizes, int n_in,
                              void* d_out, int out_size, void* d_ws, size_t ws_size,
                              hipStream_t stream) {
    const float* pred = (const float*)d_in[0];
    const int* labels = (const int*)d_in[1];
    float* out        = (float*)d_out;

    float* partial        = (float*)d_ws;              // 2048 floats
    unsigned int* counter = (unsigned int*)((char*)d_ws + GRID * sizeof(float));

    // d_ws is poisoned 0xAA before every launch; zero only the ticket counter.
    hipMemsetAsync(counter, 0, sizeof(unsigned int), stream);

    mlsm_fused<<<GRID, BLOCK, 0, stream>>>(pred, labels, partial, counter, out);
}

// Round 4
// 189.089 us; speedup vs baseline: 1.4758x; 1.4758x over previous
//
#include <hip/hip_runtime.h>

// MultiLabelSoftMax: B=4096 rows, C=8192 classes, K=8 positives/row.
// out = (1/(B*K)) * sum_{b,k} [ log(exp(p_bk) + sum_neg_b) - p_bk ]
// where sum_neg_b = sum_c exp(pred[b,c]) - sum_k exp(p_bk).
//
// Round-4: revert round-3's fused ticket (its per-block __threadfence =
// buffer_wbl2 L2-writeback serialized the whole kernel: 143 us @ 478 GB/s).
// Back to two kernels, no fences, no atomics:
//   k1: one block per row -> per-row loss in d_ws (flat body, 8 named
//       float4 loads so they all stay in flight; positive-gather issued
//       BEFORE the streaming loop to hide its latency)
//   k2: one block reduces 4096 partials -> scalar.

constexpr int B = 4096;
constexpr int C = 8192;
constexpr int K = 8;
constexpr int BLOCK = 256;                 // 4 waves of 64

__global__ __launch_bounds__(BLOCK, 2)
void mlsm_row_kernel(const float* __restrict__ pred,
                     const int* __restrict__ labels,
                     float* __restrict__ partial) {
    const int b   = blockIdx.x;
    const int tid = threadIdx.x;
    const float* row = pred + (size_t)b * C;
    const float4* row4 = reinterpret_cast<const float4*>(row);

    // Lanes 0..7: issue the scattered positive-gather FIRST so its HBM
    // latency overlaps the streaming loads below.
    float p = 0.0f;
    if (tid < K) {
        const int cls = labels[b * K + tid];
        p = row[cls];
    }

    // 8 independent float4 loads (32 elems/thread), all in flight at once.
    const float4 v0 = row4[tid + 0 * BLOCK];
    const float4 v1 = row4[tid + 1 * BLOCK];
    const float4 v2 = row4[tid + 2 * BLOCK];
    const float4 v3 = row4[tid + 3 * BLOCK];
    const float4 v4 = row4[tid + 4 * BLOCK];
    const float4 v5 = row4[tid + 5 * BLOCK];
    const float4 v6 = row4[tid + 6 * BLOCK];
    const float4 v7 = row4[tid + 7 * BLOCK];

    const float t0 = (__expf(v0.x) + __expf(v0.y)) + (__expf(v0.z) + __expf(v0.w));
    const float t1 = (__expf(v1.x) + __expf(v1.y)) + (__expf(v1.z) + __expf(v1.w));
    const float t2 = (__expf(v2.x) + __expf(v2.y)) + (__expf(v2.z) + __expf(v2.w));
    const float t3 = (__expf(v3.x) + __expf(v3.y)) + (__expf(v3.z) + __expf(v3.w));
    const float t4 = (__expf(v4.x) + __expf(v4.y)) + (__expf(v4.z) + __expf(v4.w));
    const float t5 = (__expf(v5.x) + __expf(v5.y)) + (__expf(v5.z) + __expf(v5.w));
    const float t6 = (__expf(v6.x) + __expf(v6.y)) + (__expf(v6.z) + __expf(v6.w));
    const float t7 = (__expf(v7.x) + __expf(v7.y)) + (__expf(v7.z) + __expf(v7.w));

    float s = ((t0 + t1) + (t2 + t3)) + ((t4 + t5) + (t6 + t7));

    // wave64 shuffle reduction
#pragma unroll
    for (int off = 32; off > 0; off >>= 1)
        s += __shfl_down(s, off, 64);

    __shared__ float wave_sum[BLOCK / 64];
    if ((tid & 63) == 0) wave_sum[tid >> 6] = s;
    __syncthreads();

    // Epilogue on lanes 0..7: one positive each (p already loaded).
    if (tid < K) {
        const float total =
            (wave_sum[0] + wave_sum[1]) + (wave_sum[2] + wave_sum[3]);

        const float e = __expf(p);
        float sum_pos = e;
#pragma unroll
        for (int m = 1; m < K; m <<= 1)
            sum_pos += __shfl_xor(sum_pos, m, K);

        const float sum_neg = total - sum_pos;
        float term = __logf(e + sum_neg) - p;
#pragma unroll
        for (int m = 1; m < K; m <<= 1)
            term += __shfl_xor(term, m, K);

        if (tid == 0) partial[b] = term;
    }
}

__global__ __launch_bounds__(BLOCK)
void mlsm_reduce_kernel(const float* __restrict__ partial,
                        float* __restrict__ out) {
    const int tid = threadIdx.x;
    const float4* p4 = reinterpret_cast<const float4*>(partial);

    float s = 0.f;
#pragma unroll
    for (int i = 0; i < B / 4 / BLOCK; ++i) {   // 4 float4 per thread
        float4 v = p4[tid + i * BLOCK];
        s += (v.x + v.y) + (v.z + v.w);
    }
#pragma unroll
    for (int off = 32; off > 0; off >>= 1)
        s += __shfl_down(s, off, 64);

    __shared__ float wave_sum[BLOCK / 64];
    if ((tid & 63) == 0) wave_sum[tid >> 6] = s;
    __syncthreads();

    if (tid == 0)
        out[0] = ((wave_sum[0] + wave_sum[1]) + (wave_sum[2] + wave_sum[3]))
                 * (1.0f / (float)(B * K));
}

extern "C" void kernel_launch(void* const* d_in, const int* in_sizes, int n_in,
                              void* d_out, int out_size, void* d_ws, size_t ws_size,
                              hipStream_t stream) {
    const float* pred = (const float*)d_in[0];
    const int* labels = (const int*)d_in[1];
    float* out        = (float*)d_out;
    float* partial    = (float*)d_ws;       // 4096 floats = 16 KiB

    mlsm_row_kernel<<<B, BLOCK, 0, stream>>>(pred, labels, partial);
    mlsm_reduce_kernel<<<1, BLOCK, 0, stream>>>(partial, out);
}

// Round 5
// 187.730 us; speedup vs baseline: 1.4865x; 1.0072x over previous
//
#include <hip/hip_runtime.h>

// MultiLabelSoftMax: B=4096 rows, C=8192 classes, K=8 positives/row.
// out = (1/(B*K)) * sum_{b,k} [ log(exp(p_bk) + sum_neg_b) - p_bk ]
// where sum_neg_b = sum_c exp(pred[b,c]) - sum_k exp(p_bk).
//
// Round-5: one WAVE per row (no barriers, no LDS, no atomics).
//   k1: 1024 blocks x 4 waves; wave w owns row 4*blockIdx+w. Each lane
//       streams 32 float4 (staged 8 at a time for MLP without VGPR blowup),
//       butterfly shfl_xor reduce (all lanes hold the row total), inline
//       epilogue on lanes 0..7, lane 0 writes partial[row].
//       4096 waves = 4 waves/SIMD: whole kernel co-resident in one pass.
//   k2: one block reduces 4096 partials -> scalar.

constexpr int B = 4096;
constexpr int C = 8192;
constexpr int K = 8;
constexpr int BLOCK = 256;                 // 4 waves of 64
constexpr int RPB = 4;                     // one row per wave
constexpr int GRID = B / RPB;              // 1024 blocks
constexpr int V4_PER_LANE = C / 4 / 64;    // 32 float4 per lane
constexpr int STAGE = 8;                   // loads in flight per stage

__global__ __launch_bounds__(BLOCK, 4)
void mlsm_row_kernel(const float* __restrict__ pred,
                     const int* __restrict__ labels,
                     float* __restrict__ partial) {
    const int wave = threadIdx.x >> 6;
    const int lane = threadIdx.x & 63;
    const int b    = blockIdx.x * RPB + wave;
    const float* row = pred + (size_t)b * C;
    const float4* row4 = reinterpret_cast<const float4*>(row);

    // Scattered positive-gather issued first: latency hidden under streaming.
    float p = 0.0f;
    if (lane < K) p = row[labels[b * K + lane]];

    float s0 = 0.f, s1 = 0.f, s2 = 0.f, s3 = 0.f;
#pragma unroll
    for (int g = 0; g < V4_PER_LANE / STAGE; ++g) {
        float4 v[STAGE];
#pragma unroll
        for (int i = 0; i < STAGE; ++i)
            v[i] = row4[lane + (g * STAGE + i) * 64];
#pragma unroll
        for (int i = 0; i < STAGE; ++i) {
            s0 += __expf(v[i].x);
            s1 += __expf(v[i].y);
            s2 += __expf(v[i].z);
            s3 += __expf(v[i].w);
        }
    }
    float s = (s0 + s1) + (s2 + s3);

    // Butterfly: every lane ends up with the full row sum (no LDS needed).
#pragma unroll
    for (int m = 1; m < 64; m <<= 1)
        s += __shfl_xor(s, m, 64);

    // Epilogue on lanes 0..7 of this wave (p already in register).
    if (lane < K) {
        const float e = __expf(p);
        float sum_pos = e;
#pragma unroll
        for (int m = 1; m < K; m <<= 1)
            sum_pos += __shfl_xor(sum_pos, m, K);

        const float sum_neg = s - sum_pos;
        float term = __logf(e + sum_neg) - p;
#pragma unroll
        for (int m = 1; m < K; m <<= 1)
            term += __shfl_xor(term, m, K);

        if (lane == 0) partial[b] = term;
    }
}

__global__ __launch_bounds__(BLOCK)
void mlsm_reduce_kernel(const float* __restrict__ partial,
                        float* __restrict__ out) {
    const int tid = threadIdx.x;
    const float4* p4 = reinterpret_cast<const float4*>(partial);

    float s = 0.f;
#pragma unroll
    for (int i = 0; i < B / 4 / BLOCK; ++i) {   // 4 float4 per thread
        float4 v = p4[tid + i * BLOCK];
        s += (v.x + v.y) + (v.z + v.w);
    }
#pragma unroll
    for (int off = 32; off > 0; off >>= 1)
        s += __shfl_down(s, off, 64);

    __shared__ float wave_sum[BLOCK / 64];
    if ((tid & 63) == 0) wave_sum[tid >> 6] = s;
    __syncthreads();

    if (tid == 0)
        out[0] = ((wave_sum[0] + wave_sum[1]) + (wave_sum[2] + wave_sum[3]))
                 * (1.0f / (float)(B * K));
}

extern "C" void kernel_launch(void* const* d_in, const int* in_sizes, int n_in,
                              void* d_out, int out_size, void* d_ws, size_t ws_size,
                              hipStream_t stream) {
    const float* pred = (const float*)d_in[0];
    const int* labels = (const int*)d_in[1];
    float* out        = (float*)d_out;
    float* partial    = (float*)d_ws;       // 4096 floats = 16 KiB

    mlsm_row_kernel<<<GRID, BLOCK, 0, stream>>>(pred, labels, partial);
    mlsm_reduce_kernel<<<1, BLOCK, 0, stream>>>(partial, out);
}